// Round 1
// baseline (253.134 us; speedup 1.0000x reference)
//
#include <hip/hip_runtime.h>
#include <math.h>

#define B 2
#define N 10000
#define H 8
#define HC 32
#define UV 25
#define DD 5
#define HW 400        // N / UV
#define L 50000       // DD * N
#define UVHW 10000    // UV * HW
#define MCOL 125      // UV * DD

static __device__ __forceinline__ size_t qkv_off(int s, int b, int n, int h) {
    return ((((size_t)s * B + b) * N + n) * H + h) * HC;
}

// ---------------- Kernel 1: grouped QK^T -> aw2[b][l][h][25] ----------------
__global__ __launch_bounds__(256) void k_qk(const float* __restrict__ qkv,
                                            const int* __restrict__ attn_idx,
                                            float* __restrict__ aw2) {
    const float SCALE = 0.17677669529663687f; // 1/sqrt(32)
    int bid = blockIdx.x;               // over B*DD*HW = 4000
    int b = bid / (DD * HW);
    int rem = bid % (DD * HW);
    int d = rem / HW, w = rem % HW;
    int t = threadIdx.x;

    __shared__ int idx[UV];
    __shared__ float qs[UV][HC + 1];
    __shared__ float ks[UV][HC + 1];

    if (t < UV) idx[t] = attn_idx[(d * UV + t) * HW + w];
    __syncthreads();

    for (int h = 0; h < H; ++h) {
        for (int e = t; e < UV * HC; e += 256) {
            int u = e / HC, c = e % HC;
            qs[u][c] = qkv[qkv_off(0, b, idx[u], h) + c];
            ks[u][c] = qkv[qkv_off(1, b, idx[u], h) + c];
        }
        __syncthreads();
        for (int e = t; e < UV * UV; e += 256) {
            int u = e / UV, v = e % UV;
            float acc = 0.f;
#pragma unroll
            for (int c = 0; c < HC; ++c) acc += qs[u][c] * ks[v][c];
            int lu = (d * UV + u) * HW + w;
            aw2[(((size_t)b * L + lu) * H + h) * UV + v] = acc * SCALE;
        }
        __syncthreads();
    }
}

// ------- Kernel 2: gather(attn_inv) + mask + softmax + disp; p[b][j][h][125] -------
__global__ __launch_bounds__(256) void k_softmax(const float* __restrict__ aw2,
                                                 const int* __restrict__ attn_inv,
                                                 const void* __restrict__ maskbuf,
                                                 const float* __restrict__ disp_map,
                                                 float* __restrict__ p_ws,
                                                 float* __restrict__ disp) {
    int bid = blockIdx.x;               // over B*UVHW = 20000
    int b = bid / UVHW, j = bid % UVHW;
    int t = threadIdx.x;
    int h = t >> 5, lane = t & 31;      // 8 half-waves of 32 lanes, one head each

    __shared__ int linv[DD];
    __shared__ int s_flag;

    if (t == 0) s_flag = 0;
    if (t < DD) linv[t] = attn_inv[t * UVHW + j];
    __syncthreads();
    // detect mask encoding: int32 (widened) has all bytes at offset%4!=0 == 0
    const unsigned char* mb = (const unsigned char*)maskbuf;
    if (t < 64) {
        if (mb[4 * t + 1] | mb[4 * t + 2] | mb[4 * t + 3]) s_flag = 1;
    }
    __syncthreads();
    bool isbyte = (s_flag != 0);
    const int* mw = (const int*)maskbuf;

    float vals[4];
    float m = -INFINITY;
#pragma unroll
    for (int kk = 0; kk < 4; ++kk) {
        int e = lane + kk * 32;
        float x = -INFINITY;
        if (e < MCOL) {
            int v = e / DD, d2 = e % DD;
            int l = linv[d2];
            float raw = aw2[(((size_t)b * L + l) * H + h) * UV + v];
            int mv = isbyte ? (int)mb[(size_t)j * MCOL + e] : mw[(size_t)j * MCOL + e];
            x = mv ? raw : -INFINITY;
        }
        vals[kk] = x;
        m = fmaxf(m, x);
    }
#pragma unroll
    for (int s = 16; s >= 1; s >>= 1) m = fmaxf(m, __shfl_xor(m, s, 32));
    float sum = 0.f;
#pragma unroll
    for (int kk = 0; kk < 4; ++kk) {
        float pe = expf(vals[kk] - m);  // -inf -> 0
        vals[kk] = pe;
        sum += pe;
    }
#pragma unroll
    for (int s = 16; s >= 1; s >>= 1) sum += __shfl_xor(sum, s, 32);
    float inv = 1.0f / sum;
    float dacc = 0.f;
    size_t pb = (((size_t)b * UVHW + j) * H + h) * MCOL;
#pragma unroll
    for (int kk = 0; kk < 4; ++kk) {
        int e = lane + kk * 32;
        if (e < MCOL) {
            float pe = vals[kk] * inv;
            p_ws[pb + e] = pe;
            dacc += pe * disp_map[e];
        }
    }
#pragma unroll
    for (int s = 16; s >= 1; s >>= 1) dacc += __shfl_xor(dacc, s, 32);
    if (lane == 0) disp[((size_t)b * UVHW + j) * H + h] = dacc;
}

// ---------------- Kernel 3: gather(attn_idx2) + PV + scatter-add ----------------
__global__ __launch_bounds__(256) void k_pv(const float* __restrict__ qkv,
                                            const int* __restrict__ attn_idx,
                                            const int* __restrict__ attn_idx2,
                                            const float* __restrict__ p_ws,
                                            float* __restrict__ attn_out) {
    int bid = blockIdx.x;               // over B*DD*HW*H = 32000
    int b = bid / (DD * HW * H);
    int rem = bid % (DD * HW * H);
    int d = rem / (HW * H);
    int rem2 = rem % (HW * H);
    int w = rem2 / H, h = rem2 % H;
    int t = threadIdx.x;

    __shared__ int idxv[UV];
    __shared__ int lj[UV];
    __shared__ int ld2[UV];
    __shared__ float aw7[UV][UV + 1];
    __shared__ float vs[UV][HC + 1];

    if (t < UV) {
        int m = (d * UV + t) * HW + w;
        idxv[t] = attn_idx[m];
        int lm = attn_idx2[m];
        lj[t] = lm % UVHW;
        ld2[t] = lm / UVHW;
    }
    __syncthreads();

    for (int e = t; e < UV * UV; e += 256) {
        int u = e / UV, v = e % UV;
        aw7[u][v] = p_ws[(((size_t)b * UVHW + lj[u]) * H + h) * MCOL + v * DD + ld2[u]];
    }
    const float* vbase = qkv + (size_t)2 * B * N * H * HC;
    for (int e = t; e < UV * HC; e += 256) {
        int v = e / HC, c = e % HC;
        vs[v][c] = vbase[(((size_t)b * N + idxv[v]) * H + h) * HC + c];
    }
    __syncthreads();

    for (int e = t; e < UV * HC; e += 256) {
        int u = e / HC, c = e % HC;
        float acc = 0.f;
#pragma unroll
        for (int v = 0; v < UV; ++v) acc += aw7[u][v] * vs[v][c];
        atomicAdd(&attn_out[((size_t)b * N + idxv[u]) * (H * HC) + h * HC + c], acc);
    }
}

extern "C" void kernel_launch(void* const* d_in, const int* in_sizes, int n_in,
                              void* d_out, int out_size, void* d_ws, size_t ws_size,
                              hipStream_t stream) {
    const float* qkv      = (const float*)d_in[0];
    const float* disp_map = (const float*)d_in[1];
    const void*  mask     = d_in[2];
    const int*   attn_idx  = (const int*)d_in[3];
    const int*   attn_idx2 = (const int*)d_in[4];
    const int*   attn_inv  = (const int*)d_in[5];

    float* attn_out = (float*)d_out;                          // B*N*H*HC
    float* disp     = (float*)d_out + (size_t)B * N * H * HC; // B*UVHW*H

    float* aw2  = (float*)d_ws;                     // B*L*H*UV floats (80 MB)
    float* p_ws = aw2 + (size_t)B * L * H * UV;     // B*UVHW*H*125 floats (80 MB)

    // attn_out is accumulated via atomics -> must be zeroed every call
    hipMemsetAsync(d_out, 0, (size_t)B * N * H * HC * sizeof(float), stream);

    k_qk<<<B * DD * HW, 256, 0, stream>>>(qkv, attn_idx, aw2);
    k_softmax<<<B * UVHW, 256, 0, stream>>>(aw2, attn_inv, mask, disp_map, p_ws, disp);
    k_pv<<<B * DD * HW * H, 256, 0, stream>>>(qkv, attn_idx, attn_idx2, p_ws, attn_out);
}

// Round 3
// 242.650 us; speedup vs baseline: 1.0432x; 1.0432x over previous
//
#include <hip/hip_runtime.h>
#include <math.h>

#define B 2
#define N 10000
#define H 8
#define HC 32
#define UV 25
#define DD 5
#define HW 400        // N / UV
#define L 50000       // DD * N
#define UVHW 10000    // UV * HW
#define MCOL 125      // UV * DD

static __device__ __forceinline__ size_t qkv_off(int s, int b, int n, int h) {
    return ((((size_t)s * B + b) * N + n) * H + h) * HC;
}

// ---------------- Kernel 0: invert attn_idx2 permutation ----------------
__global__ __launch_bounds__(256) void k_inv(const int* __restrict__ attn_idx2,
                                             int* __restrict__ inv2) {
    int i = blockIdx.x * 256 + threadIdx.x;
    if (i < L) inv2[attn_idx2[i]] = i;
}

// ---------------- Kernel 1: grouped QK^T -> aw2[b][l][h][25] ----------------
__global__ __launch_bounds__(256) void k_qk(const float* __restrict__ qkv,
                                            const int* __restrict__ attn_idx,
                                            float* __restrict__ aw2) {
    const float SCALE = 0.17677669529663687f; // 1/sqrt(32)
    int bid = blockIdx.x;               // over B*DD*HW = 4000
    int b = bid / (DD * HW);
    int rem = bid % (DD * HW);
    int d = rem / HW, w = rem % HW;
    int t = threadIdx.x;

    __shared__ int idx[UV];
    __shared__ float qs[UV][HC + 1];
    __shared__ float ks[UV][HC + 1];

    if (t < UV) idx[t] = attn_idx[(d * UV + t) * HW + w];
    __syncthreads();

    for (int h = 0; h < H; ++h) {
        // float4 loads: 2 * 25 rows * 8 float4 = 400 slots, strided over 256 threads
        for (int e0 = t; e0 < 2 * UV * (HC / 4); e0 += 256) {
            int which = e0 / (UV * (HC / 4));
            int e = e0 % (UV * (HC / 4));
            int u = e / (HC / 4), c4 = e % (HC / 4);
            const float4* src = (const float4*)(qkv + qkv_off(which, b, idx[u], h)) + c4;
            float4 val = *src;
            float* dst = (which == 0 ? &qs[u][c4 * 4] : &ks[u][c4 * 4]);
            dst[0] = val.x; dst[1] = val.y; dst[2] = val.z; dst[3] = val.w;
        }
        __syncthreads();
        for (int e = t; e < UV * UV; e += 256) {
            int u = e / UV, v = e % UV;
            float acc = 0.f;
#pragma unroll
            for (int c = 0; c < HC; ++c) acc += qs[u][c] * ks[v][c];
            int lu = (d * UV + u) * HW + w;
            aw2[(((size_t)b * L + lu) * H + h) * UV + v] = acc * SCALE;
        }
        __syncthreads();
    }
}

// ------- Kernel 2: gather(attn_inv) + mask + softmax + disp; scatter p3[b][m][h][25] -------
__global__ __launch_bounds__(256) void k_softmax(const float* __restrict__ aw2,
                                                 const int* __restrict__ attn_inv,
                                                 const int* __restrict__ inv2,
                                                 const void* __restrict__ maskbuf,
                                                 const float* __restrict__ disp_map,
                                                 float* __restrict__ p3,
                                                 float* __restrict__ disp) {
    int bid = blockIdx.x;               // over B*UVHW = 20000
    int b = bid / UVHW, j = bid % UVHW;
    int t = threadIdx.x;
    int h = t >> 5, lane = t & 31;      // 8 half-waves of 32 lanes, one head each

    __shared__ int linv[DD];
    __shared__ int minv2[DD];
    __shared__ int s_flag;
    __shared__ float sp[DD][H][UV];     // staged p for coalesced scatter

    if (t == 0) s_flag = 0;
    if (t < DD) {
        linv[t] = attn_inv[t * UVHW + j];
        minv2[t] = inv2[t * UVHW + j];
    }
    __syncthreads();
    // detect mask encoding: int32 (widened) has all bytes at offset%4!=0 == 0
    const unsigned char* mb = (const unsigned char*)maskbuf;
    if (t < 64) {
        if (mb[4 * t + 1] | mb[4 * t + 2] | mb[4 * t + 3]) s_flag = 1;
    }
    __syncthreads();
    bool isbyte = (s_flag != 0);
    const int* mw = (const int*)maskbuf;

    float vals[4];
    float m = -INFINITY;
#pragma unroll
    for (int kk = 0; kk < 4; ++kk) {
        int e = lane + kk * 32;
        float x = -INFINITY;
        if (e < MCOL) {
            int v = e / DD, d2 = e % DD;
            int l = linv[d2];
            float raw = aw2[(((size_t)b * L + l) * H + h) * UV + v];
            int mv = isbyte ? (int)mb[(size_t)j * MCOL + e] : mw[(size_t)j * MCOL + e];
            x = mv ? raw : -INFINITY;
        }
        vals[kk] = x;
        m = fmaxf(m, x);
    }
#pragma unroll
    for (int s = 16; s >= 1; s >>= 1) m = fmaxf(m, __shfl_xor(m, s, 32));
    float sum = 0.f;
#pragma unroll
    for (int kk = 0; kk < 4; ++kk) {
        float pe = expf(vals[kk] - m);  // -inf -> 0
        vals[kk] = pe;
        sum += pe;
    }
#pragma unroll
    for (int s = 16; s >= 1; s >>= 1) sum += __shfl_xor(sum, s, 32);
    float inv = 1.0f / sum;
    float dacc = 0.f;
#pragma unroll
    for (int kk = 0; kk < 4; ++kk) {
        int e = lane + kk * 32;
        if (e < MCOL) {
            float pe = vals[kk] * inv;
            int v = e / DD, d2 = e % DD;
            sp[d2][h][v] = pe;
            dacc += pe * disp_map[e];
        }
    }
#pragma unroll
    for (int s = 16; s >= 1; s >>= 1) dacc += __shfl_xor(dacc, s, 32);
    if (lane == 0) disp[((size_t)b * UVHW + j) * H + h] = dacc;
    __syncthreads();
    // coalesced scatter: 5 chunks of 800 contiguous bytes (one per d2 -> row m)
    for (int e2 = t; e2 < DD * H * UV; e2 += 256) {
        int d2 = e2 / (H * UV);
        int r = e2 % (H * UV);
        int h2 = r / UV, v2 = r % UV;
        p3[(((size_t)b * L + minv2[d2]) * H + h2) * UV + v2] = sp[d2][h2][v2];
    }
}

// ---------------- Kernel 3: contiguous p3 + PV + scatter-add ----------------
__global__ __launch_bounds__(256) void k_pv(const float* __restrict__ qkv,
                                            const int* __restrict__ attn_idx,
                                            const float* __restrict__ p3,
                                            float* __restrict__ attn_out) {
    int bid = blockIdx.x;               // over B*DD*HW*H = 32000
    int b = bid / (DD * HW * H);
    int rem = bid % (DD * HW * H);
    int d = rem / (HW * H);
    int rem2 = rem % (HW * H);
    int w = rem2 / H, h = rem2 % H;
    int t = threadIdx.x;

    __shared__ int idxv[UV];
    __shared__ float aw7[UV][UV + 1];
    __shared__ float vs[UV][HC + 1];

    if (t < UV) idxv[t] = attn_idx[(d * UV + t) * HW + w];
    __syncthreads();

    // p3 rows are contiguous 100-B chunks now
    for (int e = t; e < UV * UV; e += 256) {
        int u = e / UV, v = e % UV;
        int m = (d * UV + u) * HW + w;
        aw7[u][v] = p3[(((size_t)b * L + m) * H + h) * UV + v];
    }
    const float* vbase = qkv + (size_t)2 * B * N * H * HC;
    if (t < UV * (HC / 4)) {
        int v = t / (HC / 4), c4 = t % (HC / 4);
        const float4* src = (const float4*)(vbase + (((size_t)b * N + idxv[v]) * H + h) * HC) + c4;
        float4 val = *src;
        vs[v][c4 * 4 + 0] = val.x; vs[v][c4 * 4 + 1] = val.y;
        vs[v][c4 * 4 + 2] = val.z; vs[v][c4 * 4 + 3] = val.w;
    }
    __syncthreads();

    for (int e = t; e < UV * HC; e += 256) {
        int u = e / HC, c = e % HC;
        float acc = 0.f;
#pragma unroll
        for (int v = 0; v < UV; ++v) acc += aw7[u][v] * vs[v][c];
        atomicAdd(&attn_out[((size_t)b * N + idxv[u]) * (H * HC) + h * HC + c], acc);
    }
}

extern "C" void kernel_launch(void* const* d_in, const int* in_sizes, int n_in,
                              void* d_out, int out_size, void* d_ws, size_t ws_size,
                              hipStream_t stream) {
    const float* qkv      = (const float*)d_in[0];
    const float* disp_map = (const float*)d_in[1];
    const void*  mask     = d_in[2];
    const int*   attn_idx  = (const int*)d_in[3];
    const int*   attn_idx2 = (const int*)d_in[4];
    const int*   attn_inv  = (const int*)d_in[5];

    float* attn_out = (float*)d_out;                          // B*N*H*HC
    float* disp     = (float*)d_out + (size_t)B * N * H * HC; // B*UVHW*H

    float* aw2 = (float*)d_ws;                      // B*L*H*UV floats (80 MB)
    float* p3  = aw2 + (size_t)B * L * H * UV;      // B*L*H*UV floats (80 MB)
    int*   inv2 = (int*)(p3 + (size_t)B * L * H * UV); // L ints (0.2 MB)

    // attn_out is accumulated via atomics -> must be zeroed every call
    hipMemsetAsync(d_out, 0, (size_t)B * N * H * HC * sizeof(float), stream);

    k_inv<<<(L + 255) / 256, 256, 0, stream>>>(attn_idx2, inv2);
    k_qk<<<B * DD * HW, 256, 0, stream>>>(qkv, attn_idx, aw2);
    k_softmax<<<B * UVHW, 256, 0, stream>>>(aw2, attn_inv, inv2, mask, disp_map, p3, disp);
    k_pv<<<B * DD * HW * H, 256, 0, stream>>>(qkv, attn_idx, p3, attn_out);
}